// Round 9
// baseline (180.331 us; speedup 1.0000x reference)
//
#include <hip/hip_runtime.h>

// 2-layer GCN collapsed to scalar per-node quantities (verified R2):
//   dis = 1/sqrt(deg+1);  y = x*dis;  t[d] = sum_{e->d} y[src]
//   s = dis*(t+y);  z = dis * sum_j relu(s*W1[j]+b1[j])*W2[j]
//   out[d] = dis[d]*(sum_{e->d} z[src] + z[d]) + b2
//
// R8->R9: aggregation passes dominate (~35us each, floor ~8). Fixes:
// (a) grid 392->784 blocks (3/CU load balance), TBA 512->256, RSLS 2->4;
// (b) 16-way gather batching (full per-thread share in flight);
// (c) nontemporal packedB streams (save L1 for val[] gathers).
// part_k: grid 2048, TPT 2048/KPT 8 (shorter rank chains, more blocks).

#define SB_BITS 11
#define SBK     2048          // nodes per bucket
#define MAXB    64            // bucket bound (N <= 131072)
#define TBP     256           // part_k block size
#define NAPB    2048          // part_k grid
#define TPT     2048          // part_k tile (8 edges/thread)
#define KPT     8
#define NW      4             // waves per part_k block
#define NSET    4             // independent cursor/region sets
#define GSTRIDE 8             // u32 stride between cursors (32B granule)
#define RSLS    4             // slices per (bucket,set) segment
#define RSL     (NSET*RSLS)   // partial rows per bucket = 16
#define TBA     256           // aggregation block size

__device__ inline void lds_addf(float* p, float v) {
    __hip_atomic_fetch_add(p, v, __ATOMIC_RELAXED, __HIP_MEMORY_SCOPE_WORKGROUP);
}

// Partition: edges -> packedB[b*cap + set*capS + pos], bucket-contiguous.
__global__ __launch_bounds__(TBP) void part_k(
        const int* __restrict__ src, const int* __restrict__ dst, int E,
        int cap, int capS, unsigned* __restrict__ gcur,
        unsigned* __restrict__ packedB) {
    __shared__ unsigned sp[TPT];
    __shared__ unsigned char sbk[TPT];
    __shared__ unsigned woff[NW][MAXB];   // per-wave hist -> excl wave offset
    __shared__ unsigned cnt2[NW][MAXB];   // per-wave rank cursors
    __shared__ unsigned scn[MAXB];        // exclusive tile scan
    __shared__ unsigned gbase[MAXB];      // global claimed base
    const int t = threadIdx.x;
    const int w = t >> 6;
    const int lane = t & 63;
    const int set = blockIdx.x & (NSET - 1);
    int CH = (E + (int)gridDim.x - 1) / (int)gridDim.x;
    int cs = blockIdx.x * CH;
    int ce = min(cs + CH, E);
    for (int ts = cs; ts < ce; ts += TPT) {
        int tcnt = min(TPT, ce - ts);
        if (t < MAXB) {
            #pragma unroll
            for (int ww = 0; ww < NW; ww++) { woff[ww][t] = 0u; cnt2[ww][t] = 0u; }
        }
        __syncthreads();
        unsigned es[KPT], ed[KPT]; int nk = 0;
        #pragma unroll
        for (int k = 0; k < KPT; k++) {
            int j = ts + t + k * TBP;
            if (j < ce) {
                es[k] = (unsigned)__builtin_nontemporal_load(src + j);
                ed[k] = (unsigned)__builtin_nontemporal_load(dst + j);
                atomicAdd(&woff[w][ed[k] >> SB_BITS], 1u);   // per-wave hist
                nk = k + 1;
            }
        }
        __syncthreads();
        if (t < MAXB) {   // wave 0: wave offsets, set-strided claim, shfl scan
            unsigned h0 = woff[0][t], h1 = woff[1][t], h2 = woff[2][t], h3 = woff[3][t];
            woff[0][t] = 0u; woff[1][t] = h0; woff[2][t] = h0 + h1;
            woff[3][t] = h0 + h1 + h2;
            unsigned th = h0 + h1 + h2 + h3;
            gbase[t] = th ? atomicAdd(&gcur[(t * NSET + set) * GSTRIDE], th) : 0u;
            unsigned v = th;
            #pragma unroll
            for (int off = 1; off < 64; off <<= 1) {
                unsigned u = __shfl_up(v, off, 64);
                if (lane >= off) v += u;
            }
            scn[t] = v - th;   // exclusive bucket start within tile
        }
        __syncthreads();
        for (int k = 0; k < nk; k++) {   // rank + stage sorted
            unsigned b = ed[k] >> SB_BITS;
            unsigned r = scn[b] + woff[w][b] + atomicAdd(&cnt2[w][b], 1u);
            sp[r]  = es[k] | ((ed[k] & (SBK - 1u)) << 17);
            sbk[r] = (unsigned char)b;
        }
        __syncthreads();
        #pragma unroll
        for (int k = 0; k < KPT; k++) {  // coalesced write-out
            int j2 = t + k * TBP;
            if (j2 < tcnt) {
                unsigned b = sbk[j2];
                unsigned gpos = gbase[b] + (unsigned)j2 - scn[b];
                if (gpos < (unsigned)capS)   // overflow guard (per-set region)
                    packedB[(size_t)b * cap + (size_t)set * capS + gpos] = sp[j2];
            }
        }
        __syncthreads();
    }
}

// Degree partials: grid NB*NSET*RSLS. LDS u32 accumulator per segment slice.
__global__ __launch_bounds__(TBA) void degp_k(
        const unsigned* __restrict__ packedB, const unsigned* __restrict__ gcur,
        int cap, int capS, int PLN, unsigned* __restrict__ dpart) {
    __shared__ unsigned acc[SBK];
    for (int i = threadIdx.x; i < SBK; i += TBA) acc[i] = 0u;
    __syncthreads();
    int vb = blockIdx.x / RSLS, rs = blockIdx.x % RSLS;
    int b = vb >> 2, set = vb & 3;
    unsigned cnt = min(gcur[(b * NSET + set) * GSTRIDE], (unsigned)capS);
    unsigned per = (cnt + RSLS - 1) / RSLS;
    unsigned s = rs * per, e = min(s + per, cnt);
    const unsigned* p = packedB + (size_t)b * cap + (size_t)set * capS;
    unsigned j = s + threadIdx.x;
    for (; j + 15 * TBA < e; j += 16 * TBA) {
        unsigned pk[16];
        #pragma unroll
        for (int k = 0; k < 16; k++) pk[k] = __builtin_nontemporal_load(p + j + k * TBA);
        #pragma unroll
        for (int k = 0; k < 16; k++) atomicAdd(&acc[pk[k] >> 17], 1u);
    }
    for (; j < e; j += TBA) atomicAdd(&acc[p[j] >> 17], 1u);
    __syncthreads();
    int r = set * RSLS + rs;
    unsigned* o = dpart + (size_t)r * PLN + (size_t)b * SBK;
    for (int i = threadIdx.x; i < SBK; i += TBA) o[i] = acc[i];
}

// Float gather-accumulate partials (y-pass and z-pass).
__global__ __launch_bounds__(TBA) void gaccp_k(
        const unsigned* __restrict__ packedB, const unsigned* __restrict__ gcur,
        const float* __restrict__ val, int cap, int capS, int PLN,
        float* __restrict__ fpart) {
    __shared__ float acc[SBK];
    for (int i = threadIdx.x; i < SBK; i += TBA) acc[i] = 0.0f;
    __syncthreads();
    int vb = blockIdx.x / RSLS, rs = blockIdx.x % RSLS;
    int b = vb >> 2, set = vb & 3;
    unsigned cnt = min(gcur[(b * NSET + set) * GSTRIDE], (unsigned)capS);
    unsigned per = (cnt + RSLS - 1) / RSLS;
    unsigned s = rs * per, e = min(s + per, cnt);
    const unsigned* p = packedB + (size_t)b * cap + (size_t)set * capS;
    unsigned j = s + threadIdx.x;
    for (; j + 15 * TBA < e; j += 16 * TBA) {
        unsigned pk[16];
        float v[16];
        #pragma unroll
        for (int k = 0; k < 16; k++) pk[k] = __builtin_nontemporal_load(p + j + k * TBA);
        #pragma unroll
        for (int k = 0; k < 16; k++) v[k] = val[pk[k] & 0x1FFFFu];
        #pragma unroll
        for (int k = 0; k < 16; k++) lds_addf(&acc[pk[k] >> 17], v[k]);
    }
    for (; j < e; j += TBA) {
        unsigned pk = p[j];
        lds_addf(&acc[pk >> 17], val[pk & 0x1FFFFu]);
    }
    __syncthreads();
    int r = set * RSLS + rs;
    float* o = fpart + (size_t)r * PLN + (size_t)b * SBK;
    for (int i = threadIdx.x; i < SBK; i += TBA) o[i] = acc[i];
}

// deg-reduce + dis + y
__global__ void prep1_k(const unsigned* __restrict__ dpart,
                        const float* __restrict__ x, int N, int PLN,
                        float* __restrict__ dis, float* __restrict__ y) {
    int i = blockIdx.x * blockDim.x + threadIdx.x;
    if (i >= N) return;
    unsigned d = 1u;   // self loop
    #pragma unroll
    for (int r = 0; r < RSL; r++) d += dpart[(size_t)r * PLN + i];
    float rr = 1.0f / sqrtf((float)d);
    dis[i] = rr;
    y[i] = x[i] * rr;
}

// t-reduce + per-node MLP: z = dis * sum_j relu(s*W1[j]+b1[j])*W2[j]
__global__ void prep2_k(const float* __restrict__ tpart,
                        const float* __restrict__ dis,
                        const float* __restrict__ y,
                        const float* __restrict__ W1,
                        const float* __restrict__ b1,
                        const float* __restrict__ W2,
                        float* __restrict__ z, int N, int H, int PLN) {
    extern __shared__ float smem[];
    float* sW1 = smem;
    float* sb1 = smem + H;
    float* sW2 = smem + 2 * H;
    for (int j = threadIdx.x; j < H; j += blockDim.x) {
        sW1[j] = W1[j]; sb1[j] = b1[j]; sW2[j] = W2[j];
    }
    __syncthreads();
    int i = blockIdx.x * blockDim.x + threadIdx.x;
    if (i >= N) return;
    float tt = 0.0f;
    #pragma unroll
    for (int r = 0; r < RSL; r++) tt += tpart[(size_t)r * PLN + i];
    float rr = dis[i];
    float s = rr * (tt + y[i]);
    float g = 0.0f;
    const float4* w1v = (const float4*)sW1;
    const float4* b1v = (const float4*)sb1;
    const float4* w2v = (const float4*)sW2;
    #pragma unroll 8
    for (int jj = 0; jj < H / 4; jj++) {
        float4 a = w1v[jj], bb = b1v[jj], c = w2v[jj];
        float h0 = fmaf(s, a.x, bb.x); h0 = h0 > 0.0f ? h0 : 0.0f;
        float h1 = fmaf(s, a.y, bb.y); h1 = h1 > 0.0f ? h1 : 0.0f;
        float h2 = fmaf(s, a.z, bb.z); h2 = h2 > 0.0f ? h2 : 0.0f;
        float h3 = fmaf(s, a.w, bb.w); h3 = h3 > 0.0f ? h3 : 0.0f;
        g = fmaf(h0, c.x, g); g = fmaf(h1, c.y, g);
        g = fmaf(h2, c.z, g); g = fmaf(h3, c.w, g);
    }
    z[i] = g * rr;
}

// z-reduce + epilogue
__global__ void finout_k(const float* __restrict__ zpart,
                         const float* __restrict__ dis,
                         const float* __restrict__ z,
                         const float* __restrict__ b2, int N, int PLN,
                         float* __restrict__ out) {
    int i = blockIdx.x * blockDim.x + threadIdx.x;
    if (i >= N) return;
    float u = 0.0f;
    #pragma unroll
    for (int r = 0; r < RSL; r++) u += zpart[(size_t)r * PLN + i];
    out[i] = dis[i] * (u + z[i]) + b2[0];
}

extern "C" void kernel_launch(void* const* d_in, const int* in_sizes, int n_in,
                              void* d_out, int out_size, void* d_ws, size_t ws_size,
                              hipStream_t stream) {
    const float* x   = (const float*)d_in[0];
    const int*   ei  = (const int*)d_in[1];     // int32 (JAX x64-off)
    const float* W1  = (const float*)d_in[2];
    const float* b1  = (const float*)d_in[3];
    const float* W2  = (const float*)d_in[4];
    const float* b2  = (const float*)d_in[5];
    float*       out = (float*)d_out;

    const int N = in_sizes[0];        // 100000
    const int E = in_sizes[1] / 2;    // 3200000
    const int H = in_sizes[2];        // 256

    const int* srcp = ei;
    const int* dstp = ei + E;

    const int NB   = (N + SBK - 1) >> SB_BITS;           // 49
    const int PLN  = NB * SBK;                           // 100352
    const int capS = E / (NB * NSET) + 3584;             // per-set slack ~28 sigma
    const int cap  = capS * NSET;

    // workspace (u32 units):
    // [gcur 2048 (set-strided cursors)][dis N][y N][z N][partials RSL*PLN][packedB NB*cap]
    unsigned* W  = (unsigned*)d_ws;
    unsigned* gcur = W;
    float*    dis  = (float*)(W + 2048);
    float*    y    = (float*)(W + 2048 + (size_t)N);
    float*    z    = (float*)(W + 2048 + (size_t)2 * N);
    unsigned* part = W + 2048 + (size_t)3 * N;                // RSL*PLN
    unsigned* packedB = part + (size_t)RSL * PLN;             // NB*cap

    hipMemsetAsync(gcur, 0, 2048 * sizeof(unsigned), stream);

    const int gN = (N + 255) / 256;
    const int gA = NB * NSET * RSLS;

    part_k <<<NAPB, TBP, 0, stream>>>(srcp, dstp, E, cap, capS, gcur, packedB);
    degp_k <<<gA, TBA, 0, stream>>>(packedB, gcur, cap, capS, PLN, part);
    prep1_k<<<gN, 256, 0, stream>>>(part, x, N, PLN, dis, y);
    gaccp_k<<<gA, TBA, 0, stream>>>(packedB, gcur, y, cap, capS, PLN, (float*)part);
    prep2_k<<<gN, 256, (size_t)3 * H * sizeof(float), stream>>>(
        (float*)part, dis, y, W1, b1, W2, z, N, H, PLN);
    gaccp_k<<<gA, TBA, 0, stream>>>(packedB, gcur, z, cap, capS, PLN, (float*)part);
    finout_k<<<gN, 256, 0, stream>>>((float*)part, dis, z, b2, N, PLN, out);
}